// Round 15
// baseline (66.591 us; speedup 1.0000x reference)
//
#include <hip/hip_runtime.h>
#include <cstdint>
#include <cstddef>

// Problem constants: B=16, S=512, DEG=8, D=512, L=64
#define DDIM   512
#define NNODES 8192      // B*S
#define NEDGE  65536     // B*S*DEG
#define PCOLS  1536      // 3*D
#define NKT    16        // K=512 / BK=32
#define TILE_SHORTS 4096 // one (128-row x 32-k) bf16 tile = [4 kb][128 row][8]

typedef __attribute__((ext_vector_type(8))) short bf16x8;
typedef __attribute__((ext_vector_type(4))) float f32x4;

#define AS1 __attribute__((address_space(1)))
#define AS3 __attribute__((address_space(3)))

static __device__ __forceinline__ unsigned short f2bf(float f) {
    unsigned u = __float_as_uint(f);
    u += 0x7FFFu + ((u >> 16) & 1u);   // round-to-nearest-even
    return (unsigned short)(u >> 16);
}

static __device__ __forceinline__ void unpack8(uint4 pv, float* pf) {
    const unsigned* pw = (const unsigned*)&pv;
    pf[0] = __uint_as_float(pw[0] << 16); pf[1] = __uint_as_float(pw[0] & 0xffff0000u);
    pf[2] = __uint_as_float(pw[1] << 16); pf[3] = __uint_as_float(pw[1] & 0xffff0000u);
    pf[4] = __uint_as_float(pw[2] << 16); pf[5] = __uint_as_float(pw[2] & 0xffff0000u);
    pf[6] = __uint_as_float(pw[3] << 16); pf[7] = __uint_as_float(pw[3] & 0xffff0000u);
}

// ---------------------------------------------------------------------------
// Kernel 1 (merged, 512 thr): identical to R12.
//   blocks [0,1024):       x -> tiled bf16 A-operand (xbt) + 3 gate dots
//   blocks [1024,1216):    Wcat^T tiled bf16 (192 transpose blocks)
//   blocks [1216,1248):    b_in/b_out -> bf16 row-major tables
// ---------------------------------------------------------------------------
__global__ __launch_bounds__(512) void prep_kernel(
    const float* __restrict__ src,
    const float* __restrict__ vg_in, const float* __restrict__ vg_out,
    const float* __restrict__ vg_loop,
    const float* __restrict__ v_in, const float* __restrict__ v_out,
    const float* __restrict__ w_loop, const float* __restrict__ b_in,
    const float* __restrict__ b_out,
    unsigned short* __restrict__ xbt, unsigned short* __restrict__ wct,
    unsigned short* __restrict__ bb_in, unsigned short* __restrict__ bb_out,
    float* __restrict__ g_in, float* __restrict__ g_out, float* __restrict__ g_loop)
{
    __shared__ float tile[64][65];
    if (blockIdx.x < 1024) {
        int lane = threadIdx.x & 63;
        int row  = blockIdx.x * 8 + (threadIdx.x >> 6);
        int j0   = lane * 8;

        const float* x = src + (size_t)row * DDIM + j0;
        float4 x0 = *(const float4*)x;
        float4 x1 = *(const float4*)(x + 4);
        float xs[8] = {x0.x, x0.y, x0.z, x0.w, x1.x, x1.y, x1.z, x1.w};

        alignas(16) unsigned short h[8];
#pragma unroll
        for (int i = 0; i < 8; ++i) h[i] = f2bf(xs[i]);
        int tm = row >> 7, rw = row & 127;
        size_t off = ((size_t)(tm * NKT + (lane >> 2))) * TILE_SHORTS
                   + ((size_t)(lane & 3) * 128 + rw) * 8;
        *(uint4*)(xbt + off) = *(const uint4*)h;

        float s0 = 0.f, s1 = 0.f, s2 = 0.f;
#pragma unroll
        for (int i = 0; i < 8; ++i) {
            s0 += xs[i] * vg_in[j0 + i];
            s1 += xs[i] * vg_out[j0 + i];
            s2 += xs[i] * vg_loop[j0 + i];
        }
#pragma unroll
        for (int o = 32; o > 0; o >>= 1) {
            s0 += __shfl_xor(s0, o);
            s1 += __shfl_xor(s1, o);
            s2 += __shfl_xor(s2, o);
        }
        if (lane == 0) { g_in[row] = s0; g_out[row] = s1; g_loop[row] = s2; }
    } else if (blockIdx.x < 1216) {
        int bb = blockIdx.x - 1024;       // 0..191
        int kc = bb / 24;                 // 0..7  (64-k chunk)
        int nt = bb % 24;                 // 0..23 (64-n chunk of Wcat)
        int k0 = kc * 64;

        const float* srcp; int nl0 = (nt & 7) * 64;
        if      (nt < 8)  srcp = v_in;
        else if (nt < 16) srcp = v_out;
        else              srcp = w_loop;

        int c  = threadIdx.x & 63;
        int rr = threadIdx.x >> 6;        // 0..7
#pragma unroll
        for (int i = 0; i < 8; ++i) {
            int kk = i * 8 + rr;
            tile[kk][c] = srcp[(size_t)(k0 + kk) * DDIM + nl0 + c];
        }
        __syncthreads();
        int tn = nt >> 1;
        int nrbase = (nt & 1) * 64;
        int idx = threadIdx.x;
        int nn  = idx >> 3;
        int k8  = idx & 7;                // 8-elem k-group within 64
        int ktl = k8 >> 2;                // which 32-k tile (0/1)
        int kb  = k8 & 3;
        size_t tb = ((size_t)(tn * NKT + kc * 2 + ktl)) * TILE_SHORTS;
        alignas(16) unsigned short h[8];
#pragma unroll
        for (int e = 0; e < 8; ++e) h[e] = f2bf(tile[k8 * 8 + e][nn]);
        *(uint4*)(wct + tb + ((size_t)kb * 128 + nrbase + nn) * 8) = *(const uint4*)h;
    } else {
        // bias tables -> bf16 (2 x 64 x 512)
        int i = (blockIdx.x - 1216) * 512 + threadIdx.x;   // 0..16383
        int base = i * 4;
        int which = base >> 15;
        int off   = base & 32767;
        const float* s = which ? b_out : b_in;
        unsigned short* d = which ? bb_out : bb_in;
        float4 v = *(const float4*)(s + off);
        alignas(8) unsigned short h[4] = {f2bf(v.x), f2bf(v.y), f2bf(v.z), f2bf(v.w)};
        *(uint2*)(d + off) = *(const uint2*)h;
    }
}

// ---------------------------------------------------------------------------
// Kernel 2: GEMM, identical to R12 (ring-3 + counted vmcnt + LDS-transposed
// contiguous epilogue).
// ---------------------------------------------------------------------------
#define EP_STRIDE 136   // shorts; 272 B rows, 16-B aligned for b128 reads

__global__ __launch_bounds__(512, 6) void gemmp_kernel(
    const unsigned short* __restrict__ At,
    const unsigned short* __restrict__ Bt,
    unsigned short* __restrict__ P)
{
    __shared__ short lds[24576];

    int tid  = threadIdx.x;
    int lane = tid & 63;
    int wid  = tid >> 6;                    // 0..7
    int bid  = blockIdx.x;
    int local = bid >> 3;                   // 0..95
    int tm    = (bid & 7) * 8 + local / 12; // 64 tm panels, 8 per XCD
    int tn    = local % 12;
    int row0 = tm * 128, col0 = tn * 128;
    int wm   = wid >> 2, wn = wid & 3;      // 2m x 4n waves, each 64 x 32
    int r16  = lane & 15, kq = lane >> 4;

    f32x4 acc[4][2];
#pragma unroll
    for (int m = 0; m < 4; ++m)
#pragma unroll
        for (int n = 0; n < 2; ++n) acc[m][n] = (f32x4){0.f, 0.f, 0.f, 0.f};

    const unsigned short* ga = At + (size_t)(tm * NKT) * TILE_SHORTS;
    const unsigned short* gb = Bt + (size_t)(tn * NKT) * TILE_SHORTS;

    auto stage = [&](int buf, int kt) {
        size_t kt8 = (size_t)kt * TILE_SHORTS;
        __builtin_amdgcn_global_load_lds(
            (const AS1 void*)(ga + kt8 + tid * 8),
            (AS3 void*)(&lds[buf * 4096 + wid * 512]), 16, 0, 0);
        __builtin_amdgcn_global_load_lds(
            (const AS1 void*)(gb + kt8 + tid * 8),
            (AS3 void*)(&lds[12288 + buf * 4096 + wid * 512]), 16, 0, 0);
    };

    auto compute = [&](int buf) {
        const short* la = &lds[buf * 4096];
        const short* lb = &lds[12288 + buf * 4096];
        bf16x8 af[4], bfr[2];
#pragma unroll
        for (int m = 0; m < 4; ++m)
            af[m] = *(const bf16x8*)(la + (kq * 128 + wm * 64 + m * 16 + r16) * 8);
#pragma unroll
        for (int n = 0; n < 2; ++n)
            bfr[n] = *(const bf16x8*)(lb + (kq * 128 + wn * 32 + n * 16 + r16) * 8);
#pragma unroll
        for (int m = 0; m < 4; ++m)
#pragma unroll
            for (int n = 0; n < 2; ++n)
                acc[m][n] = __builtin_amdgcn_mfma_f32_16x16x32_bf16(
                    af[m], bfr[n], acc[m][n], 0, 0, 0);
        __builtin_amdgcn_sched_barrier(0);
        __builtin_amdgcn_s_barrier();           // release buffer for restaging
    };

    stage(0, 0); stage(1, 1);

    int bufc = 0;
    for (int t = 0; t < 14; ++t) {
        int bufs = bufc + 2; if (bufs >= 3) bufs -= 3;
        stage(bufs, t + 2);
        asm volatile("s_waitcnt vmcnt(4)" ::: "memory");
        __builtin_amdgcn_sched_barrier(0);
        __builtin_amdgcn_s_barrier();
        __builtin_amdgcn_sched_barrier(0);
        compute(bufc);
        ++bufc; if (bufc == 3) bufc = 0;
    }
    asm volatile("s_waitcnt vmcnt(2)" ::: "memory");
    __builtin_amdgcn_sched_barrier(0);
    __builtin_amdgcn_s_barrier();
    __builtin_amdgcn_sched_barrier(0);
    compute(bufc);                                  // t=14
    ++bufc; if (bufc == 3) bufc = 0;
    asm volatile("s_waitcnt vmcnt(0)" ::: "memory");
    __builtin_amdgcn_sched_barrier(0);
    __builtin_amdgcn_s_barrier();
    __builtin_amdgcn_sched_barrier(0);
    compute(bufc);                                  // t=15

    // LDS-transposed C epilogue
#pragma unroll
    for (int m = 0; m < 4; ++m) {
        int lrow = wm * 64 + m * 16 + kq * 4;
#pragma unroll
        for (int n = 0; n < 2; ++n) {
            int lcol = wn * 32 + n * 16 + r16;
#pragma unroll
            for (int r = 0; r < 4; ++r)
                lds[(lrow + r) * EP_STRIDE + lcol] = f2bf(acc[m][n][r]);
        }
    }
    __syncthreads();
#pragma unroll
    for (int p = 0; p < 4; ++p) {
        int row  = p * 32 + (tid >> 4);
        int col8 = (tid & 15) * 8;
        bf16x8 v = *(const bf16x8*)&lds[row * EP_STRIDE + col8];
        *(bf16x8*)(P + (size_t)(row0 + row) * PCOLS + col0 + col8) = v;
    }
}

// ---------------------------------------------------------------------------
// Kernel 3: fused aggregate. SINGLE CHANGE vs R12: branch-free gathers with
// masked-edge redirect. sn[k] = mask ? src : n (v_cndmask, no branch) — the
// dummy gather hits the node's OWN P row (L1/L2-hot, ~zero extra L3 traffic)
// and FMA multiplies by w=0 exactly. All 16 P-gathers per wave issue
// back-to-back -> ~16 outstanding loads instead of ~1 (control-serialized).
// ---------------------------------------------------------------------------
__global__ __launch_bounds__(512) void aggf_kernel(
    const unsigned short* __restrict__ P,
    const float* __restrict__ g_in, const float* __restrict__ g_out,
    const float* __restrict__ g_loop,
    const int* __restrict__ arc_in, const int* __restrict__ lbl_in,
    const int* __restrict__ arc_out, const int* __restrict__ lbl_out,
    const float* __restrict__ mask_in, const float* __restrict__ mask_out,
    const float* __restrict__ mask_loop, const float* __restrict__ sent_mask,
    const unsigned short* __restrict__ bb_in, const unsigned short* __restrict__ bb_out,
    const float* __restrict__ bg_in, const float* __restrict__ bg_out,
    const float* __restrict__ ln_g, const float* __restrict__ ln_b,
    const float* __restrict__ src, float* __restrict__ out)
{
    int lane = threadIdx.x & 63;
    int n    = blockIdx.x * 8 + (threadIdx.x >> 6);
    int j0   = lane * 8;
    int e0   = n * 8;

    float acc[8] = {0,0,0,0,0,0,0,0};

    // ---- phase 1: in-edges, branch-free with dummy-redirect ----
    {
        int sn[8], lb[8]; float w[8];
#pragma unroll
        for (int k = 0; k < 8; ++k) {
            sn[k] = arc_in[e0 + k] * 512 + arc_in[NEDGE + e0 + k];
            lb[k] = lbl_in[e0 + k];
            w[k]  = mask_in[e0 + k];
        }
#pragma unroll
        for (int k = 0; k < 8; ++k) {
            w[k]  = w[k] / (1.0f + __expf(-(g_in[sn[k]] + bg_in[lb[k]])));
            sn[k] = (w[k] != 0.f) ? sn[k] : n;     // cndmask, no branch
        }
#pragma unroll
        for (int k = 0; k < 8; ++k) {
            uint4 pv = *(const uint4*)(P + (size_t)sn[k] * PCOLS + j0);
            uint4 bv = *(const uint4*)(bb_in + (size_t)lb[k] * DDIM + j0);
            float pf[8], bf[8]; unpack8(pv, pf); unpack8(bv, bf);
#pragma unroll
            for (int i = 0; i < 8; ++i) acc[i] += w[k] * (pf[i] + bf[i]);
        }
    }
    // ---- phase 2: out-edges, branch-free with dummy-redirect ----
    {
        int sn[8], lb[8]; float w[8];
#pragma unroll
        for (int k = 0; k < 8; ++k) {
            sn[k] = arc_out[e0 + k] * 512 + arc_out[NEDGE + e0 + k];
            lb[k] = lbl_out[e0 + k];
            w[k]  = mask_out[e0 + k];
        }
#pragma unroll
        for (int k = 0; k < 8; ++k) {
            w[k]  = w[k] / (1.0f + __expf(-(g_out[sn[k]] + bg_out[lb[k]])));
            sn[k] = (w[k] != 0.f) ? sn[k] : n;
        }
#pragma unroll
        for (int k = 0; k < 8; ++k) {
            uint4 pv = *(const uint4*)(P + (size_t)sn[k] * PCOLS + 512 + j0);
            uint4 bv = *(const uint4*)(bb_out + (size_t)lb[k] * DDIM + j0);
            float pf[8], bf[8]; unpack8(pv, pf); unpack8(bv, bf);
#pragma unroll
            for (int i = 0; i < 8; ++i) acc[i] += w[k] * (pf[i] + bf[i]);
        }
    }
    // ---- self-loop ----
    {
        float wl = mask_loop[n] / (1.0f + __expf(-g_loop[n]));
        uint4 pv = *(const uint4*)(P + (size_t)n * PCOLS + 1024 + j0);
        float pf[8]; unpack8(pv, pf);
#pragma unroll
        for (int i = 0; i < 8; ++i) acc[i] += wl * pf[i];
    }

    // LayerNorm over D=512 within the wave
    float sum = 0.f, sq = 0.f;
#pragma unroll
    for (int i = 0; i < 8; ++i) { sum += acc[i]; sq += acc[i] * acc[i]; }
#pragma unroll
    for (int o = 32; o > 0; o >>= 1) {
        sum += __shfl_xor(sum, o);
        sq  += __shfl_xor(sq, o);
    }
    float mu   = sum * (1.0f / 512.0f);
    float var  = sq * (1.0f / 512.0f) - mu * mu;
    float rstd = rsqrtf(var + 1e-5f);
    float sm   = sent_mask[n];

    float4 gg0 = *(const float4*)(ln_g + j0);
    float4 gg1 = *(const float4*)(ln_g + j0 + 4);
    float4 be0 = *(const float4*)(ln_b + j0);
    float4 be1 = *(const float4*)(ln_b + j0 + 4);
    const float* sr = src + (size_t)n * DDIM + j0;
    float4 s0 = *(const float4*)sr;
    float4 s1 = *(const float4*)(sr + 4);
    float gl[8] = {gg0.x, gg0.y, gg0.z, gg0.w, gg1.x, gg1.y, gg1.z, gg1.w};
    float bt[8] = {be0.x, be0.y, be0.z, be0.w, be1.x, be1.y, be1.z, be1.w};
    float srs[8] = {s0.x, s0.y, s0.z, s0.w, s1.x, s1.y, s1.z, s1.w};

    float o_[8];
#pragma unroll
    for (int i = 0; i < 8; ++i) {
        float v = (acc[i] - mu) * rstd * gl[i] + bt[i];
        v *= sm;
        v = fmaxf(v, 0.f);
        o_[i] = v * sm + srs[i];
    }
    float4 w0 = {o_[0], o_[1], o_[2], o_[3]};
    float4 w1 = {o_[4], o_[5], o_[6], o_[7]};
    float* op = out + (size_t)n * DDIM + j0;
    *(float4*)op = w0;
    *(float4*)(op + 4) = w1;
}

// ---------------------------------------------------------------------------
// Workspace layout: identical to R12.
//   xbt   : 0           (8,388,608)
//   wct   : 8,388,608   (1,572,864)
//   bb_in : 9,961,472   (65,536)
//   bb_out: 10,027,008  (65,536)
//   g_in  : 10,092,544  (32,768)
//   g_out : 10,125,312  (32,768)
//   g_loop: 10,158,080  (32,768)
//   P     : 10,190,848  (25,165,824)
// ---------------------------------------------------------------------------
extern "C" void kernel_launch(void* const* d_in, const int* in_sizes, int n_in,
                              void* d_out, int out_size, void* d_ws, size_t ws_size,
                              hipStream_t stream)
{
    const float* src       = (const float*)d_in[0];
    const int*   arc_in    = (const int*)d_in[1];
    const int*   lbl_in    = (const int*)d_in[2];
    const int*   arc_out   = (const int*)d_in[3];
    const int*   lbl_out   = (const int*)d_in[4];
    const float* mask_in   = (const float*)d_in[5];
    const float* mask_out  = (const float*)d_in[6];
    const float* mask_loop = (const float*)d_in[7];
    const float* sent_mask = (const float*)d_in[8];
    const float* V_in      = (const float*)d_in[9];
    const float* b_in      = (const float*)d_in[10];
    const float* Vg_in     = (const float*)d_in[11];
    const float* bg_in     = (const float*)d_in[12];
    const float* V_out     = (const float*)d_in[13];
    const float* b_out     = (const float*)d_in[14];
    const float* Vg_out    = (const float*)d_in[15];
    const float* bg_out    = (const float*)d_in[16];
    const float* W_loop    = (const float*)d_in[17];
    const float* Wg_loop   = (const float*)d_in[18];
    const float* ln_g      = (const float*)d_in[19];
    const float* ln_b      = (const float*)d_in[20];

    uint8_t* ws = (uint8_t*)d_ws;
    unsigned short* xbt   = (unsigned short*)(ws);
    unsigned short* wct   = (unsigned short*)(ws + 8388608);
    unsigned short* bb_in = (unsigned short*)(ws + 9961472);
    unsigned short* bb_out= (unsigned short*)(ws + 10027008);
    float*          g_in  = (float*)(ws + 10092544);
    float*          g_out = (float*)(ws + 10125312);
    float*          g_lp  = (float*)(ws + 10158080);
    unsigned short* P     = (unsigned short*)(ws + 10190848);

    prep_kernel<<<1248, 512, 0, stream>>>(src, Vg_in, Vg_out, Wg_loop,
                                          V_in, V_out, W_loop, b_in, b_out,
                                          xbt, wct, bb_in, bb_out,
                                          g_in, g_out, g_lp);
    gemmp_kernel<<<768, 512, 0, stream>>>(xbt, wct, P);
    aggf_kernel<<<1024, 512, 0, stream>>>(P, g_in, g_out, g_lp,
                                          arc_in, lbl_in, arc_out, lbl_out,
                                          mask_in, mask_out, mask_loop, sent_mask,
                                          bb_in, bb_out, bg_in, bg_out,
                                          ln_g, ln_b, src, (float*)d_out);
}

// Round 16
// 52.479 us; speedup vs baseline: 1.2689x; 1.2689x over previous
//
#include <hip/hip_runtime.h>
#include <cstdint>
#include <cstddef>

// Problem constants: B=16, S=512, DEG=8, D=512, L=64
#define DDIM   512
#define NNODES 8192      // B*S
#define NEDGE  65536     // B*S*DEG
#define PCOLS  1536      // 3*D
#define NKT    16        // K=512 / BK=32
#define TILE_SHORTS 4096 // one (128-row x 32-k) bf16 tile = [4 kb][128 row][8]

typedef __attribute__((ext_vector_type(8))) short bf16x8;
typedef __attribute__((ext_vector_type(4))) float f32x4;

#define AS1 __attribute__((address_space(1)))
#define AS3 __attribute__((address_space(3)))

static __device__ __forceinline__ unsigned short f2bf(float f) {
    unsigned u = __float_as_uint(f);
    u += 0x7FFFu + ((u >> 16) & 1u);   // round-to-nearest-even
    return (unsigned short)(u >> 16);
}

static __device__ __forceinline__ void unpack8(uint4 pv, float* pf) {
    const unsigned* pw = (const unsigned*)&pv;
    pf[0] = __uint_as_float(pw[0] << 16); pf[1] = __uint_as_float(pw[0] & 0xffff0000u);
    pf[2] = __uint_as_float(pw[1] << 16); pf[3] = __uint_as_float(pw[1] & 0xffff0000u);
    pf[4] = __uint_as_float(pw[2] << 16); pf[5] = __uint_as_float(pw[2] & 0xffff0000u);
    pf[6] = __uint_as_float(pw[3] << 16); pf[7] = __uint_as_float(pw[3] & 0xffff0000u);
}

// ---------------------------------------------------------------------------
// Kernel 1 (merged, 512 thr): identical to R12.
//   blocks [0,1024):       x -> tiled bf16 A-operand (xbt) + 3 gate dots
//   blocks [1024,1216):    Wcat^T tiled bf16 (192 transpose blocks)
//   blocks [1216,1248):    b_in/b_out -> bf16 row-major tables
// ---------------------------------------------------------------------------
__global__ __launch_bounds__(512) void prep_kernel(
    const float* __restrict__ src,
    const float* __restrict__ vg_in, const float* __restrict__ vg_out,
    const float* __restrict__ vg_loop,
    const float* __restrict__ v_in, const float* __restrict__ v_out,
    const float* __restrict__ w_loop, const float* __restrict__ b_in,
    const float* __restrict__ b_out,
    unsigned short* __restrict__ xbt, unsigned short* __restrict__ wct,
    unsigned short* __restrict__ bb_in, unsigned short* __restrict__ bb_out,
    float* __restrict__ g_in, float* __restrict__ g_out, float* __restrict__ g_loop)
{
    __shared__ float tile[64][65];
    if (blockIdx.x < 1024) {
        int lane = threadIdx.x & 63;
        int row  = blockIdx.x * 8 + (threadIdx.x >> 6);
        int j0   = lane * 8;

        const float* x = src + (size_t)row * DDIM + j0;
        float4 x0 = *(const float4*)x;
        float4 x1 = *(const float4*)(x + 4);
        float xs[8] = {x0.x, x0.y, x0.z, x0.w, x1.x, x1.y, x1.z, x1.w};

        alignas(16) unsigned short h[8];
#pragma unroll
        for (int i = 0; i < 8; ++i) h[i] = f2bf(xs[i]);
        int tm = row >> 7, rw = row & 127;
        size_t off = ((size_t)(tm * NKT + (lane >> 2))) * TILE_SHORTS
                   + ((size_t)(lane & 3) * 128 + rw) * 8;
        *(uint4*)(xbt + off) = *(const uint4*)h;

        float s0 = 0.f, s1 = 0.f, s2 = 0.f;
#pragma unroll
        for (int i = 0; i < 8; ++i) {
            s0 += xs[i] * vg_in[j0 + i];
            s1 += xs[i] * vg_out[j0 + i];
            s2 += xs[i] * vg_loop[j0 + i];
        }
#pragma unroll
        for (int o = 32; o > 0; o >>= 1) {
            s0 += __shfl_xor(s0, o);
            s1 += __shfl_xor(s1, o);
            s2 += __shfl_xor(s2, o);
        }
        if (lane == 0) { g_in[row] = s0; g_out[row] = s1; g_loop[row] = s2; }
    } else if (blockIdx.x < 1216) {
        int bb = blockIdx.x - 1024;       // 0..191
        int kc = bb / 24;                 // 0..7  (64-k chunk)
        int nt = bb % 24;                 // 0..23 (64-n chunk of Wcat)
        int k0 = kc * 64;

        const float* srcp; int nl0 = (nt & 7) * 64;
        if      (nt < 8)  srcp = v_in;
        else if (nt < 16) srcp = v_out;
        else              srcp = w_loop;

        int c  = threadIdx.x & 63;
        int rr = threadIdx.x >> 6;        // 0..7
#pragma unroll
        for (int i = 0; i < 8; ++i) {
            int kk = i * 8 + rr;
            tile[kk][c] = srcp[(size_t)(k0 + kk) * DDIM + nl0 + c];
        }
        __syncthreads();
        int tn = nt >> 1;
        int nrbase = (nt & 1) * 64;
        int idx = threadIdx.x;
        int nn  = idx >> 3;
        int k8  = idx & 7;                // 8-elem k-group within 64
        int ktl = k8 >> 2;                // which 32-k tile (0/1)
        int kb  = k8 & 3;
        size_t tb = ((size_t)(tn * NKT + kc * 2 + ktl)) * TILE_SHORTS;
        alignas(16) unsigned short h[8];
#pragma unroll
        for (int e = 0; e < 8; ++e) h[e] = f2bf(tile[k8 * 8 + e][nn]);
        *(uint4*)(wct + tb + ((size_t)kb * 128 + nrbase + nn) * 8) = *(const uint4*)h;
    } else {
        // bias tables -> bf16 (2 x 64 x 512)
        int i = (blockIdx.x - 1216) * 512 + threadIdx.x;   // 0..16383
        int base = i * 4;
        int which = base >> 15;
        int off   = base & 32767;
        const float* s = which ? b_out : b_in;
        unsigned short* d = which ? bb_out : bb_in;
        float4 v = *(const float4*)(s + off);
        alignas(8) unsigned short h[4] = {f2bf(v.x), f2bf(v.y), f2bf(v.z), f2bf(v.w)};
        *(uint2*)(d + off) = *(const uint2*)h;
    }
}

// ---------------------------------------------------------------------------
// Kernel 2: GEMM, identical to R12 (ring-3 + counted vmcnt + LDS-transposed
// contiguous epilogue).
// ---------------------------------------------------------------------------
#define EP_STRIDE 136   // shorts; 272 B rows, 16-B aligned for b128 reads

__global__ __launch_bounds__(512, 6) void gemmp_kernel(
    const unsigned short* __restrict__ At,
    const unsigned short* __restrict__ Bt,
    unsigned short* __restrict__ P)
{
    __shared__ short lds[24576];

    int tid  = threadIdx.x;
    int lane = tid & 63;
    int wid  = tid >> 6;                    // 0..7
    int bid  = blockIdx.x;
    int local = bid >> 3;                   // 0..95
    int tm    = (bid & 7) * 8 + local / 12; // 64 tm panels, 8 per XCD
    int tn    = local % 12;
    int row0 = tm * 128, col0 = tn * 128;
    int wm   = wid >> 2, wn = wid & 3;      // 2m x 4n waves, each 64 x 32
    int r16  = lane & 15, kq = lane >> 4;

    f32x4 acc[4][2];
#pragma unroll
    for (int m = 0; m < 4; ++m)
#pragma unroll
        for (int n = 0; n < 2; ++n) acc[m][n] = (f32x4){0.f, 0.f, 0.f, 0.f};

    const unsigned short* ga = At + (size_t)(tm * NKT) * TILE_SHORTS;
    const unsigned short* gb = Bt + (size_t)(tn * NKT) * TILE_SHORTS;

    auto stage = [&](int buf, int kt) {
        size_t kt8 = (size_t)kt * TILE_SHORTS;
        __builtin_amdgcn_global_load_lds(
            (const AS1 void*)(ga + kt8 + tid * 8),
            (AS3 void*)(&lds[buf * 4096 + wid * 512]), 16, 0, 0);
        __builtin_amdgcn_global_load_lds(
            (const AS1 void*)(gb + kt8 + tid * 8),
            (AS3 void*)(&lds[12288 + buf * 4096 + wid * 512]), 16, 0, 0);
    };

    auto compute = [&](int buf) {
        const short* la = &lds[buf * 4096];
        const short* lb = &lds[12288 + buf * 4096];
        bf16x8 af[4], bfr[2];
#pragma unroll
        for (int m = 0; m < 4; ++m)
            af[m] = *(const bf16x8*)(la + (kq * 128 + wm * 64 + m * 16 + r16) * 8);
#pragma unroll
        for (int n = 0; n < 2; ++n)
            bfr[n] = *(const bf16x8*)(lb + (kq * 128 + wn * 32 + n * 16 + r16) * 8);
#pragma unroll
        for (int m = 0; m < 4; ++m)
#pragma unroll
            for (int n = 0; n < 2; ++n)
                acc[m][n] = __builtin_amdgcn_mfma_f32_16x16x32_bf16(
                    af[m], bfr[n], acc[m][n], 0, 0, 0);
        __builtin_amdgcn_sched_barrier(0);
        __builtin_amdgcn_s_barrier();           // release buffer for restaging
    };

    stage(0, 0); stage(1, 1);

    int bufc = 0;
    for (int t = 0; t < 14; ++t) {
        int bufs = bufc + 2; if (bufs >= 3) bufs -= 3;
        stage(bufs, t + 2);
        asm volatile("s_waitcnt vmcnt(4)" ::: "memory");
        __builtin_amdgcn_sched_barrier(0);
        __builtin_amdgcn_s_barrier();
        __builtin_amdgcn_sched_barrier(0);
        compute(bufc);
        ++bufc; if (bufc == 3) bufc = 0;
    }
    asm volatile("s_waitcnt vmcnt(2)" ::: "memory");
    __builtin_amdgcn_sched_barrier(0);
    __builtin_amdgcn_s_barrier();
    __builtin_amdgcn_sched_barrier(0);
    compute(bufc);                                  // t=14
    ++bufc; if (bufc == 3) bufc = 0;
    asm volatile("s_waitcnt vmcnt(0)" ::: "memory");
    __builtin_amdgcn_sched_barrier(0);
    __builtin_amdgcn_s_barrier();
    __builtin_amdgcn_sched_barrier(0);
    compute(bufc);                                  // t=15

    // LDS-transposed C epilogue
#pragma unroll
    for (int m = 0; m < 4; ++m) {
        int lrow = wm * 64 + m * 16 + kq * 4;
#pragma unroll
        for (int n = 0; n < 2; ++n) {
            int lcol = wn * 32 + n * 16 + r16;
#pragma unroll
            for (int r = 0; r < 4; ++r)
                lds[(lrow + r) * EP_STRIDE + lcol] = f2bf(acc[m][n][r]);
        }
    }
    __syncthreads();
#pragma unroll
    for (int p = 0; p < 4; ++p) {
        int row  = p * 32 + (tid >> 4);
        int col8 = (tid & 15) * 8;
        bf16x8 v = *(const bf16x8*)&lds[row * EP_STRIDE + col8];
        *(bf16x8*)(P + (size_t)(row0 + row) * PCOLS + col0 + col8) = v;
    }
}

// ---------------------------------------------------------------------------
// Kernel 3: fused aggregate. Body identical to R12 (one wave/node, mask-skip,
// wave-uniform branches). SINGLE CHANGE: __launch_bounds__(512, 8) caps the
// allocator at 64 VGPR so 8 waves/SIMD (4 blocks/CU) can be resident —
// doubling the outstanding-gather concurrency for this latency-bound kernel.
// ---------------------------------------------------------------------------
__global__ __launch_bounds__(512, 8) void aggf_kernel(
    const unsigned short* __restrict__ P,
    const float* __restrict__ g_in, const float* __restrict__ g_out,
    const float* __restrict__ g_loop,
    const int* __restrict__ arc_in, const int* __restrict__ lbl_in,
    const int* __restrict__ arc_out, const int* __restrict__ lbl_out,
    const float* __restrict__ mask_in, const float* __restrict__ mask_out,
    const float* __restrict__ mask_loop, const float* __restrict__ sent_mask,
    const unsigned short* __restrict__ bb_in, const unsigned short* __restrict__ bb_out,
    const float* __restrict__ bg_in, const float* __restrict__ bg_out,
    const float* __restrict__ ln_g, const float* __restrict__ ln_b,
    const float* __restrict__ src, float* __restrict__ out)
{
    int lane = threadIdx.x & 63;
    int n    = blockIdx.x * 8 + (threadIdx.x >> 6);
    int j0   = lane * 8;

    float acc[8] = {0,0,0,0,0,0,0,0};

#pragma unroll
    for (int k = 0; k < 8; ++k) {
        int e  = n * 8 + k;                    // wave-uniform
        float mk = mask_in[e];
        if (mk != 0.f) {                        // wave-uniform branch
            int sn = arc_in[e] * 512 + arc_in[NEDGE + e];
            int lb = lbl_in[e];
            float w = mk / (1.0f + __expf(-(g_in[sn] + bg_in[lb])));
            uint4 pv = *(const uint4*)(P + (size_t)sn * PCOLS + j0);
            uint4 bv = *(const uint4*)(bb_in + (size_t)lb * DDIM + j0);
            float pf[8], bf[8]; unpack8(pv, pf); unpack8(bv, bf);
#pragma unroll
            for (int i = 0; i < 8; ++i) acc[i] += w * (pf[i] + bf[i]);
        }
    }
#pragma unroll
    for (int k = 0; k < 8; ++k) {
        int e  = n * 8 + k;
        float mk = mask_out[e];
        if (mk != 0.f) {
            int sn = arc_out[e] * 512 + arc_out[NEDGE + e];
            int lb = lbl_out[e];
            float w = mk / (1.0f + __expf(-(g_out[sn] + bg_out[lb])));
            uint4 pv = *(const uint4*)(P + (size_t)sn * PCOLS + 512 + j0);
            uint4 bv = *(const uint4*)(bb_out + (size_t)lb * DDIM + j0);
            float pf[8], bf[8]; unpack8(pv, pf); unpack8(bv, bf);
#pragma unroll
            for (int i = 0; i < 8; ++i) acc[i] += w * (pf[i] + bf[i]);
        }
    }
    {
        float wl = mask_loop[n] / (1.0f + __expf(-g_loop[n]));
        uint4 pv = *(const uint4*)(P + (size_t)n * PCOLS + 1024 + j0);
        float pf[8]; unpack8(pv, pf);
#pragma unroll
        for (int i = 0; i < 8; ++i) acc[i] += wl * pf[i];
    }

    // LayerNorm over D=512 within the wave
    float sum = 0.f, sq = 0.f;
#pragma unroll
    for (int i = 0; i < 8; ++i) { sum += acc[i]; sq += acc[i] * acc[i]; }
#pragma unroll
    for (int o = 32; o > 0; o >>= 1) {
        sum += __shfl_xor(sum, o);
        sq  += __shfl_xor(sq, o);
    }
    float mu   = sum * (1.0f / 512.0f);
    float var  = sq * (1.0f / 512.0f) - mu * mu;
    float rstd = rsqrtf(var + 1e-5f);
    float sm   = sent_mask[n];

    float4 gg0 = *(const float4*)(ln_g + j0);
    float4 gg1 = *(const float4*)(ln_g + j0 + 4);
    float4 be0 = *(const float4*)(ln_b + j0);
    float4 be1 = *(const float4*)(ln_b + j0 + 4);
    const float* sr = src + (size_t)n * DDIM + j0;
    float4 s0 = *(const float4*)sr;
    float4 s1 = *(const float4*)(sr + 4);
    float gl[8] = {gg0.x, gg0.y, gg0.z, gg0.w, gg1.x, gg1.y, gg1.z, gg1.w};
    float bt[8] = {be0.x, be0.y, be0.z, be0.w, be1.x, be1.y, be1.z, be1.w};
    float srs[8] = {s0.x, s0.y, s0.z, s0.w, s1.x, s1.y, s1.z, s1.w};

    float o_[8];
#pragma unroll
    for (int i = 0; i < 8; ++i) {
        float v = (acc[i] - mu) * rstd * gl[i] + bt[i];
        v *= sm;
        v = fmaxf(v, 0.f);
        o_[i] = v * sm + srs[i];
    }
    float4 w0 = {o_[0], o_[1], o_[2], o_[3]};
    float4 w1 = {o_[4], o_[5], o_[6], o_[7]};
    float* op = out + (size_t)n * DDIM + j0;
    *(float4*)op = w0;
    *(float4*)(op + 4) = w1;
}

// ---------------------------------------------------------------------------
// Workspace layout: identical to R12.
//   xbt   : 0           (8,388,608)
//   wct   : 8,388,608   (1,572,864)
//   bb_in : 9,961,472   (65,536)
//   bb_out: 10,027,008  (65,536)
//   g_in  : 10,092,544  (32,768)
//   g_out : 10,125,312  (32,768)
//   g_loop: 10,158,080  (32,768)
//   P     : 10,190,848  (25,165,824)
// ---------------------------------------------------------------------------
extern "C" void kernel_launch(void* const* d_in, const int* in_sizes, int n_in,
                              void* d_out, int out_size, void* d_ws, size_t ws_size,
                              hipStream_t stream)
{
    const float* src       = (const float*)d_in[0];
    const int*   arc_in    = (const int*)d_in[1];
    const int*   lbl_in    = (const int*)d_in[2];
    const int*   arc_out   = (const int*)d_in[3];
    const int*   lbl_out   = (const int*)d_in[4];
    const float* mask_in   = (const float*)d_in[5];
    const float* mask_out  = (const float*)d_in[6];
    const float* mask_loop = (const float*)d_in[7];
    const float* sent_mask = (const float*)d_in[8];
    const float* V_in      = (const float*)d_in[9];
    const float* b_in      = (const float*)d_in[10];
    const float* Vg_in     = (const float*)d_in[11];
    const float* bg_in     = (const float*)d_in[12];
    const float* V_out     = (const float*)d_in[13];
    const float* b_out     = (const float*)d_in[14];
    const float* Vg_out    = (const float*)d_in[15];
    const float* bg_out    = (const float*)d_in[16];
    const float* W_loop    = (const float*)d_in[17];
    const float* Wg_loop   = (const float*)d_in[18];
    const float* ln_g      = (const float*)d_in[19];
    const float* ln_b      = (const float*)d_in[20];

    uint8_t* ws = (uint8_t*)d_ws;
    unsigned short* xbt   = (unsigned short*)(ws);
    unsigned short* wct   = (unsigned short*)(ws + 8388608);
    unsigned short* bb_in = (unsigned short*)(ws + 9961472);
    unsigned short* bb_out= (unsigned short*)(ws + 10027008);
    float*          g_in  = (float*)(ws + 10092544);
    float*          g_out = (float*)(ws + 10125312);
    float*          g_lp  = (float*)(ws + 10158080);
    unsigned short* P     = (unsigned short*)(ws + 10190848);

    prep_kernel<<<1248, 512, 0, stream>>>(src, Vg_in, Vg_out, Wg_loop,
                                          V_in, V_out, W_loop, b_in, b_out,
                                          xbt, wct, bb_in, bb_out,
                                          g_in, g_out, g_lp);
    gemmp_kernel<<<768, 512, 0, stream>>>(xbt, wct, P);
    aggf_kernel<<<1024, 512, 0, stream>>>(P, g_in, g_out, g_lp,
                                          arc_in, lbl_in, arc_out, lbl_out,
                                          mask_in, mask_out, mask_loop, sent_mask,
                                          bb_in, bb_out, bg_in, bg_out,
                                          ln_g, ln_b, src, (float*)d_out);
}